// Round 1
// baseline (434.410 us; speedup 1.0000x reference)
//
#include <hip/hip_runtime.h>
#include <math.h>

// RandomActivation: out[r][c] = min(act(func_id[c], x[r][c]), max_output[c])
// BATCH=16384, DIM=4096, fp32 in/out. Memory-bound floor ~85us (537 MB @ 6.3 TB/s).
// v2: branchless activation select (random per-column func_id caused 5-way
// exec-mask serialization), exp-based tanh (libm tanhf is a large branchy
// routine), one __expf shared by silu/sigmoid/tanh, grid-stride with stride
// multiple of DIM/4 so func_id/max_output load once per thread.

#define RA_DIM   4096
#define RA_DIM4  (RA_DIM / 4)   // 1024, power of two
#define RA_BLOCK 256
#define RA_GRID  2048           // 2048*256 threads = 512 row-slots * 1024 col4-slots

__device__ __forceinline__ float ra_act_min(float v, int f, float m) {
    // Clamp so t*t can't overflow to inf (no-op for |v| < 44; inputs are N(0,1)).
    float vc   = fminf(fmaxf(v, -44.0f), 44.0f);
    float t    = __expf(-vc);                              // e^-v
    float sig  = __builtin_amdgcn_rcpf(1.0f + t);          // sigmoid
    float t2   = t * t;                                    // e^-2v
    float th   = (1.0f - t2) * __builtin_amdgcn_rcpf(1.0f + t2); // tanh
    float vmax = fmaxf(v, 0.0f);
    float relu = vmax;                                     // f==0
    float silu = v * sig;                                  // f==1
    float leak = vmax + 0.01f * fminf(v, 0.0f);            // f==2
    // f==3: sig, f==4: th

    float r = relu;
    r = (f == 1) ? silu : r;   // v_cmp + v_cndmask each, no branches
    r = (f == 2) ? leak : r;
    r = (f == 3) ? sig  : r;
    r = (f == 4) ? th   : r;
    return fminf(r, m);
}

__global__ __launch_bounds__(RA_BLOCK) void RandomActivation_24567212933826_kernel(
        const float4* __restrict__ x4,
        const float4* __restrict__ mo4,   // max_output, [DIM4]
        const int4*   __restrict__ fid4,  // func_id,    [DIM4]
        float4* __restrict__ out4,
        int total4) {
    int tid = blockIdx.x * RA_BLOCK + threadIdx.x;   // 0 .. 524287
    int c4  = tid & (RA_DIM4 - 1);                   // fixed column group per thread
    int r0  = tid >> 10;                             // starting row, 0..511

    // Column metadata loaded ONCE per thread (stride keeps c4 constant).
    int4   f = fid4[c4];
    float4 m = mo4[c4];

    const int stride = (RA_GRID * RA_BLOCK);         // 524288, multiple of RA_DIM4
    int idx = r0 * RA_DIM4 + c4;

    #pragma unroll 4
    for (; idx < total4; idx += stride) {
        float4 xv = x4[idx];
        float4 o;
        o.x = ra_act_min(xv.x, f.x, m.x);
        o.y = ra_act_min(xv.y, f.y, m.y);
        o.z = ra_act_min(xv.z, f.z, m.z);
        o.w = ra_act_min(xv.w, f.w, m.w);
        out4[idx] = o;
    }
}

extern "C" void kernel_launch(void* const* d_in, const int* in_sizes, int n_in,
                              void* d_out, int out_size, void* d_ws, size_t ws_size,
                              hipStream_t stream) {
    const float4* x4   = (const float4*)d_in[0];   // x [BATCH, DIM] fp32
    const float4* mo4  = (const float4*)d_in[1];   // max_output [DIM] fp32
    const int4*   fid4 = (const int4*)d_in[2];     // func_id [DIM] int32
    float4*       out4 = (float4*)d_out;

    long long total  = (long long)in_sizes[0];     // BATCH*DIM = 67108864
    int total4 = (int)(total / 4);                 // 16777216, fits int32

    RandomActivation_24567212933826_kernel<<<dim3(RA_GRID), RA_BLOCK, 0, stream>>>(
        x4, mo4, fid4, out4, total4);
}